// Round 4
// baseline (17.339 us; speedup 1.0000x reference)
//
#include <hip/hip_runtime.h>
#include <hip/hip_bf16.h>

// Fully fused, band=2. Block b = (opair, band): output channels {2*opair,+1},
// output rows {band*2, band*2+1}. Grid 64*14 = 896 blocks, 256 threads.
//
// LDS sA[c][pr][...] with channel stride 148 floats (4 padded rows * 36 + 4):
//   148 mod 32 = 20 -> the 8 c8 classes map to 8 distinct 4-bank groups
//   (20*c8 mod 32 = {0,20,8,28,16,4,24,12}) -> phase-B reads ~conflict-free.
// Phase A: 256 tasks = 64 ch x 4 padded rows, one per thread. Sliding-window
//   float4 stage-1 compute (low VGPR).
// Phase B: 224 active = 2 oo x 2 dh x 7 st x 8 c8. Each thread: 1x4 output
//   strip, 8 interleaved channels; shfl_xor reduce over c8; lane c8==0 does
//   one float4 store. No second barrier, no sRed.
__global__ __launch_bounds__(256, 4) void fused_kernel(
    const float* __restrict__ x,    // [64][28][28]
    const float* __restrict__ w1,   // [128][32][3][3][2]
    const float* __restrict__ w2,   // [64][3][2]
    float* __restrict__ y)          // [128][28][28]
{
    __shared__ __align__(16) float sA[64 * 148];   // 37,888 B

    const int b     = blockIdx.x;     // 0..895
    const int opair = b / 14;
    const int band  = b % 14;
    const int tid   = threadIdx.x;

    // ---------------- Phase A: stage1+2 into LDS ----------------
    {
        const int c  = tid >> 2;          // 0..63
        const int pr = tid & 3;           // padded row 0..3
        const int m  = band * 2 + pr - 1; // input row
        float* dst = &sA[c * 148 + pr * 36];
        if (m < 0 || m > 27) {
            #pragma unroll
            for (int t = 0; t < 7; ++t)
                ((float4*)dst)[t] = make_float4(0.f, 0.f, 0.f, 0.f);
            ((float2*)dst)[14] = make_float2(0.f, 0.f);
        } else {
            const int j0 = c & ~1;
            const int k  = c & 1;
            const float* xr0 = x + (j0 * 28 + m) * 28;
            const float* xr1 = xr0 + 28 * 28;
            const float* w2p = w2 + j0 * 6 + k;
            const float wa0 = w2p[0], wa1 = w2p[2],  wa2 = w2p[4];
            const float wb0 = w2p[6], wb1 = w2p[8],  wb2 = w2p[10];

            float4 pv0 = make_float4(0.f, 0.f, 0.f, 0.f);
            float4 pv1 = make_float4(0.f, 0.f, 0.f, 0.f);
            #pragma unroll
            for (int t = 0; t < 7; ++t) {
                float4 v0 = ((const float4*)xr0)[t];
                float4 v1 = ((const float4*)xr1)[t];
                float4 o;
                o.x = wa0 * pv0.z + wa1 * pv0.w + wa2 * v0.x
                    + wb0 * pv1.z + wb1 * pv1.w + wb2 * v1.x;
                o.y = wa0 * pv0.w + wa1 * v0.x + wa2 * v0.y
                    + wb0 * pv1.w + wb1 * v1.x + wb2 * v1.y;
                o.z = wa0 * v0.x + wa1 * v0.y + wa2 * v0.z
                    + wb0 * v1.x + wb1 * v1.y + wb2 * v1.z;
                o.w = wa0 * v0.y + wa1 * v0.z + wa2 * v0.w
                    + wb0 * v1.y + wb1 * v1.z + wb2 * v1.w;
                if (t == 0) o.x = 0.f;     // px 0 is left zero-pad
                ((float4*)dst)[t] = o;
                pv0 = v0; pv1 = v1;
            }
            // px 28 (n=27: taps r[26], r[27], 0) and px 29 (right pad)
            float t28 = wa0 * pv0.z + wa1 * pv0.w
                      + wb0 * pv1.z + wb1 * pv1.w;
            ((float2*)dst)[14] = make_float2(t28, 0.f);
        }
    }
    __syncthreads();

    // ---------------- Phase B: 3x3x64 conv, 8-way c-split ----------------
    const int oo    = tid >> 7;        // wave-pair uniform
    const int r     = tid & 127;
    const int c8    = r & 7;           // channel split (lane bits 0..2)
    const int strip = r >> 3;          // 0..15, active < 14
    const bool act  = (strip < 14);
    const int dh    = strip / 7;       // output row within band
    const int st    = strip % 7;       // 4-col strip
    const int o     = opair * 2 + oo;

    float acc0 = 0.f, acc1 = 0.f, acc2 = 0.f, acc3 = 0.f;
    if (act) {
        const float* wbo = w1 + o * 576;            // w1[o][l][r][s][k]
        #pragma unroll 2
        for (int ci = 0; ci < 8; ++ci) {
            const int c = c8 + ci * 8;              // interleaved channels
            const float* wc = wbo + (c >> 1) * 18 + (c & 1);
            const float* sa = &sA[c * 148 + st * 4];
            #pragma unroll
            for (int dy = 0; dy < 3; ++dy) {
                const float w0  = wc[dy * 6 + 0];
                const float w1v = wc[dy * 6 + 2];
                const float w2v = wc[dy * 6 + 4];
                const float* row = sa + (dh + dy) * 36;
                float4 t0 = *(const float4*)row;
                float2 t1 = *(const float2*)(row + 4);
                acc0 += w0 * t0.x + w1v * t0.y + w2v * t0.z;
                acc1 += w0 * t0.y + w1v * t0.z + w2v * t0.w;
                acc2 += w0 * t0.z + w1v * t0.w + w2v * t1.x;
                acc3 += w0 * t0.w + w1v * t1.x + w2v * t1.y;
            }
        }
    }

    // butterfly reduce over c8 (lane bits 0..2)
    #pragma unroll
    for (int m = 1; m <= 4; m <<= 1) {
        acc0 += __shfl_xor(acc0, m);
        acc1 += __shfl_xor(acc1, m);
        acc2 += __shfl_xor(acc2, m);
        acc3 += __shfl_xor(acc3, m);
    }

    if (act && c8 == 0) {
        const int R = band * 2 + dh;
        float* yp = y + (o * 28 + R) * 28 + st * 4;
        *(float4*)yp = make_float4(acc0, acc1, acc2, acc3);
    }
}

extern "C" void kernel_launch(void* const* d_in, const int* in_sizes, int n_in,
                              void* d_out, int out_size, void* d_ws, size_t ws_size,
                              hipStream_t stream) {
    const float* x  = (const float*)d_in[0];   // (1,64,28,28) fp32
    const float* w1 = (const float*)d_in[1];   // (128,32,3,3,2) fp32
    const float* w2 = (const float*)d_in[2];   // (64,3,2) fp32
    float* yout = (float*)d_out;               // (1,128,28,28) fp32

    fused_kernel<<<dim3(896), dim3(256), 0, stream>>>(x, w1, w2, yout);
}

// Round 5
// 14.713 us; speedup vs baseline: 1.1784x; 1.1784x over previous
//
#include <hip/hip_runtime.h>
#include <hip/hip_bf16.h>

// Fully fused, band=4 (the R3 winner), leaner issue path.
// Block b = (opair, band): output channels {2*opair, 2*opair+1},
// output rows band*4 .. band*4+3. Grid 64*7 = 448 blocks, 256 threads.
//
// LDS sA[c][pr][36] with channel stride 220 floats (6 rows*36 + pad 4):
//   c4 lane classes hit distinct bank groups (2*220 mod 32 = 24).
// Phase A: 384 tasks = 64 ch x 6 padded rows; sliding-window float4 stage-1.
// Phase B: oo = tid>>7, strip = (tid&127)>>2 (active<28: dh 0-3, st 0-6),
//   c4 = lane&3. Thread owns l = c4+4*li (li 0..7), BOTH channels 2l,2l+1
//   -> weights load as float2 (k pairs). 1x4 output strip.
//   2-step shfl_xor reduce over c4; lane c4==0 stores float4.
__global__ __launch_bounds__(256, 2) void fused_kernel(
    const float* __restrict__ x,    // [64][28][28]
    const float* __restrict__ w1,   // [128][32][3][3][2]
    const float* __restrict__ w2,   // [64][3][2]
    float* __restrict__ y)          // [128][28][28]
{
    __shared__ __align__(16) float sA[64 * 220];   // 56,320 B

    const int b     = blockIdx.x;     // 0..447
    const int opair = b / 7;
    const int band  = b % 7;
    const int tid   = threadIdx.x;

    // ---------------- Phase A: stage1+2 into LDS ----------------
    for (int task = tid; task < 384; task += 256) {
        const int c  = task / 6;
        const int pr = task % 6;
        const int m  = band * 4 + pr - 1;   // input row for padded row
        float* dst = &sA[c * 220 + pr * 36];
        if (m < 0 || m > 27) {
            #pragma unroll
            for (int t = 0; t < 7; ++t)
                ((float4*)dst)[t] = make_float4(0.f, 0.f, 0.f, 0.f);
            ((float2*)dst)[14] = make_float2(0.f, 0.f);
        } else {
            const int j0 = c & ~1;
            const int k  = c & 1;
            const float* xr0 = x + (j0 * 28 + m) * 28;
            const float* xr1 = xr0 + 28 * 28;
            const float* w2p = w2 + j0 * 6 + k;
            const float wa0 = w2p[0], wa1 = w2p[2],  wa2 = w2p[4];
            const float wb0 = w2p[6], wb1 = w2p[8],  wb2 = w2p[10];

            float4 pv0 = make_float4(0.f, 0.f, 0.f, 0.f);
            float4 pv1 = make_float4(0.f, 0.f, 0.f, 0.f);
            #pragma unroll
            for (int t = 0; t < 7; ++t) {
                float4 v0 = ((const float4*)xr0)[t];
                float4 v1 = ((const float4*)xr1)[t];
                float4 o;
                o.x = wa0 * pv0.z + wa1 * pv0.w + wa2 * v0.x
                    + wb0 * pv1.z + wb1 * pv1.w + wb2 * v1.x;
                o.y = wa0 * pv0.w + wa1 * v0.x + wa2 * v0.y
                    + wb0 * pv1.w + wb1 * v1.x + wb2 * v1.y;
                o.z = wa0 * v0.x + wa1 * v0.y + wa2 * v0.z
                    + wb0 * v1.x + wb1 * v1.y + wb2 * v1.z;
                o.w = wa0 * v0.y + wa1 * v0.z + wa2 * v0.w
                    + wb0 * v1.y + wb1 * v1.z + wb2 * v1.w;
                if (t == 0) o.x = 0.f;     // px 0 is left zero-pad
                ((float4*)dst)[t] = o;
                pv0 = v0; pv1 = v1;
            }
            // px 28 (taps xr[26], xr[27]) and px 29 (right pad)
            float t28 = wa0 * pv0.z + wa1 * pv0.w
                      + wb0 * pv1.z + wb1 * pv1.w;
            ((float2*)dst)[14] = make_float2(t28, 0.f);
        }
    }
    __syncthreads();

    // ---------------- Phase B: 3x3x64 conv ----------------
    const int oo    = tid >> 7;          // 0/1
    const int r     = tid & 127;
    const int c4    = r & 3;             // lane bits 0-1: l-mod-4 split
    const int strip = r >> 2;            // 0..31, active < 28
    const bool act  = (strip < 28);
    const int sclp  = act ? strip : 0;   // keep idle lanes in bounds
    const int dh    = sclp / 7;
    const int st    = sclp % 7;
    const int o     = opair * 2 + oo;

    float acc0 = 0.f, acc1 = 0.f, acc2 = 0.f, acc3 = 0.f;
    const float* wbo = w1 + o * 576;     // w1[o][l][dy][s][k]

    #pragma unroll 2
    for (int li = 0; li < 8; ++li) {
        const int l = c4 + li * 4;                 // l 0..31
        const float* w9 = wbo + l * 18;
        const float* rowA = &sA[(2 * l) * 220 + dh * 36 + st * 4];
        #pragma unroll
        for (int dy = 0; dy < 3; ++dy) {
            // weight pairs: (.x -> channel 2l, .y -> channel 2l+1) per tap s
            float2 ws0 = *(const float2*)(w9 + dy * 6 + 0);
            float2 ws1 = *(const float2*)(w9 + dy * 6 + 2);
            float2 ws2 = *(const float2*)(w9 + dy * 6 + 4);
            const float* rA = rowA + dy * 36;
            const float* rB = rA + 220;
            float4 a  = *(const float4*)rA;
            float2 a2 = *(const float2*)(rA + 4);
            float4 bb = *(const float4*)rB;
            float2 b2 = *(const float2*)(rB + 4);

            acc0 += ws0.x * a.x  + ws1.x * a.y  + ws2.x * a.z
                  + ws0.y * bb.x + ws1.y * bb.y + ws2.y * bb.z;
            acc1 += ws0.x * a.y  + ws1.x * a.z  + ws2.x * a.w
                  + ws0.y * bb.y + ws1.y * bb.z + ws2.y * bb.w;
            acc2 += ws0.x * a.z  + ws1.x * a.w  + ws2.x * a2.x
                  + ws0.y * bb.z + ws1.y * bb.w + ws2.y * b2.x;
            acc3 += ws0.x * a.w  + ws1.x * a2.x + ws2.x * a2.y
                  + ws0.y * bb.w + ws1.y * b2.x + ws2.y * b2.y;
        }
    }

    // butterfly reduce over c4 (lane bits 0-1)
    acc0 += __shfl_xor(acc0, 1); acc1 += __shfl_xor(acc1, 1);
    acc2 += __shfl_xor(acc2, 1); acc3 += __shfl_xor(acc3, 1);
    acc0 += __shfl_xor(acc0, 2); acc1 += __shfl_xor(acc1, 2);
    acc2 += __shfl_xor(acc2, 2); acc3 += __shfl_xor(acc3, 2);

    if (act && c4 == 0) {
        const int R = band * 4 + dh;
        float* yp = y + (o * 28 + R) * 28 + st * 4;
        *(float4*)yp = make_float4(acc0, acc1, acc2, acc3);
    }
}

extern "C" void kernel_launch(void* const* d_in, const int* in_sizes, int n_in,
                              void* d_out, int out_size, void* d_ws, size_t ws_size,
                              hipStream_t stream) {
    const float* x  = (const float*)d_in[0];   // (1,64,28,28) fp32
    const float* w1 = (const float*)d_in[1];   // (128,32,3,3,2) fp32
    const float* w2 = (const float*)d_in[2];   // (64,3,2) fp32
    float* yout = (float*)d_out;               // (1,128,28,28) fp32

    fused_kernel<<<dim3(448), dim3(256), 0, stream>>>(x, w1, w2, yout);
}

// Round 6
// 14.633 us; speedup vs baseline: 1.1849x; 1.0055x over previous
//
#include <hip/hip_runtime.h>
#include <hip/hip_bf16.h>

// Fully fused, band=4, 448 blocks x 256 threads.
// Block b = (opair, band): output channels {2*opair, 2*opair+1},
// output rows band*4 .. band*4+3.
//
// Phase A (R5-proven): stage1+2 into LDS sA[c][pr][36], channel stride 220.
// Weight prefetch: all 36 float2 (4 l-values x 9 taps, k-paired) loaded to
//   registers BEFORE the barrier -> latency hides under phase A.
// Phase B: thread = (oo, rp, st, l8). 2x4 output tile (rows rp*2, rp*2+1,
//   cols st*4..+3). 8-way l-split over lane bits 0-2. Per (li, ch): 4 padded
//   rows x (b128+b64) serve both output rows. 3-step shfl_xor reduce; lane
//   l8==0 stores two float4.
__global__ __launch_bounds__(256, 2) void fused_kernel(
    const float* __restrict__ x,    // [64][28][28]
    const float* __restrict__ w1,   // [128][32][3][3][2]
    const float* __restrict__ w2,   // [64][3][2]
    float* __restrict__ y)          // [128][28][28]
{
    __shared__ __align__(16) float sA[64 * 220];   // 56,320 B

    const int b     = blockIdx.x;     // 0..447
    const int opair = b / 7;
    const int band  = b % 7;
    const int tid   = threadIdx.x;

    // ---------------- Phase B thread mapping (needed for prefetch) --------
    const int l8      = tid & 7;          // lane bits 0-2: l-split
    const int strip   = tid >> 3;         // 0..31, active < 28
    const bool act    = (strip < 28);
    const int sclp    = act ? strip : 0;
    const int oo      = sclp / 14;
    const int rem     = sclp % 14;
    const int rp      = rem / 7;          // output row-pair within band
    const int st      = rem % 7;          // 4-col strip
    const int o       = opair * 2 + oo;

    // ---------------- Weight prefetch (before barrier) ----------------
    float2 wreg[4][9];
    {
        const float* wb = w1 + o * 576 + l8 * 18;   // w1[o][l][dy][s][k]
        #pragma unroll
        for (int li = 0; li < 4; ++li)
            #pragma unroll
            for (int t = 0; t < 9; ++t)
                wreg[li][t] = *(const float2*)(wb + li * 144 + t * 2);
    }

    // ---------------- Phase A: stage1+2 into LDS ----------------
    for (int task = tid; task < 384; task += 256) {
        const int c  = task / 6;
        const int pr = task % 6;
        const int m  = band * 4 + pr - 1;   // input row for padded row
        float* dst = &sA[c * 220 + pr * 36];
        if (m < 0 || m > 27) {
            #pragma unroll
            for (int t = 0; t < 7; ++t)
                ((float4*)dst)[t] = make_float4(0.f, 0.f, 0.f, 0.f);
            ((float2*)dst)[14] = make_float2(0.f, 0.f);
        } else {
            const int j0 = c & ~1;
            const int k  = c & 1;
            const float* xr0 = x + (j0 * 28 + m) * 28;
            const float* xr1 = xr0 + 28 * 28;
            const float* w2p = w2 + j0 * 6 + k;
            const float wa0 = w2p[0], wa1 = w2p[2],  wa2 = w2p[4];
            const float wb0 = w2p[6], wb1 = w2p[8],  wb2 = w2p[10];

            float4 pv0 = make_float4(0.f, 0.f, 0.f, 0.f);
            float4 pv1 = make_float4(0.f, 0.f, 0.f, 0.f);
            #pragma unroll
            for (int t = 0; t < 7; ++t) {
                float4 v0 = ((const float4*)xr0)[t];
                float4 v1 = ((const float4*)xr1)[t];
                float4 ov;
                ov.x = wa0 * pv0.z + wa1 * pv0.w + wa2 * v0.x
                     + wb0 * pv1.z + wb1 * pv1.w + wb2 * v1.x;
                ov.y = wa0 * pv0.w + wa1 * v0.x + wa2 * v0.y
                     + wb0 * pv1.w + wb1 * v1.x + wb2 * v1.y;
                ov.z = wa0 * v0.x + wa1 * v0.y + wa2 * v0.z
                     + wb0 * v1.x + wb1 * v1.y + wb2 * v1.z;
                ov.w = wa0 * v0.y + wa1 * v0.z + wa2 * v0.w
                     + wb0 * v1.y + wb1 * v1.z + wb2 * v1.w;
                if (t == 0) ov.x = 0.f;     // px 0 is left zero-pad
                ((float4*)dst)[t] = ov;
                pv0 = v0; pv1 = v1;
            }
            // px 28 (taps xr[26], xr[27]) and px 29 (right pad)
            float t28 = wa0 * pv0.z + wa1 * pv0.w
                      + wb0 * pv1.z + wb1 * pv1.w;
            ((float2*)dst)[14] = make_float2(t28, 0.f);
        }
    }
    __syncthreads();

    // ---------------- Phase B: 3x3x64 conv, 2x4 tile ----------------
    float acc00 = 0.f, acc01 = 0.f, acc02 = 0.f, acc03 = 0.f;
    float acc10 = 0.f, acc11 = 0.f, acc12 = 0.f, acc13 = 0.f;

    #pragma unroll
    for (int li = 0; li < 4; ++li) {
        #pragma unroll
        for (int ch = 0; ch < 2; ++ch) {
            const int c = (l8 + li * 8) * 2 + ch;
            const float* sa = &sA[c * 220 + (rp * 2) * 36 + st * 4];
            #pragma unroll
            for (int q = 0; q < 4; ++q) {
                float4 t0 = *(const float4*)(sa + q * 36);
                float2 t1 = *(const float2*)(sa + q * 36 + 4);
                if (q < 3) {            // output row 0, tap dy=q
                    float2 W0 = wreg[li][q * 3 + 0];
                    float2 W1 = wreg[li][q * 3 + 1];
                    float2 W2 = wreg[li][q * 3 + 2];
                    float wa = ch ? W0.y : W0.x;
                    float wbv = ch ? W1.y : W1.x;
                    float wc = ch ? W2.y : W2.x;
                    acc00 += wa * t0.x + wbv * t0.y + wc * t0.z;
                    acc01 += wa * t0.y + wbv * t0.z + wc * t0.w;
                    acc02 += wa * t0.z + wbv * t0.w + wc * t1.x;
                    acc03 += wa * t0.w + wbv * t1.x + wc * t1.y;
                }
                if (q >= 1) {           // output row 1, tap dy=q-1
                    float2 W0 = wreg[li][(q - 1) * 3 + 0];
                    float2 W1 = wreg[li][(q - 1) * 3 + 1];
                    float2 W2 = wreg[li][(q - 1) * 3 + 2];
                    float wa = ch ? W0.y : W0.x;
                    float wbv = ch ? W1.y : W1.x;
                    float wc = ch ? W2.y : W2.x;
                    acc10 += wa * t0.x + wbv * t0.y + wc * t0.z;
                    acc11 += wa * t0.y + wbv * t0.z + wc * t0.w;
                    acc12 += wa * t0.z + wbv * t0.w + wc * t1.x;
                    acc13 += wa * t0.w + wbv * t1.x + wc * t1.y;
                }
            }
        }
    }

    // butterfly reduce over l8 (lane bits 0-2)
    #pragma unroll
    for (int m = 1; m <= 4; m <<= 1) {
        acc00 += __shfl_xor(acc00, m); acc01 += __shfl_xor(acc01, m);
        acc02 += __shfl_xor(acc02, m); acc03 += __shfl_xor(acc03, m);
        acc10 += __shfl_xor(acc10, m); acc11 += __shfl_xor(acc11, m);
        acc12 += __shfl_xor(acc12, m); acc13 += __shfl_xor(acc13, m);
    }

    if (act && l8 == 0) {
        const int R0 = band * 4 + rp * 2;
        float* yp = y + (o * 28 + R0) * 28 + st * 4;
        *(float4*)yp        = make_float4(acc00, acc01, acc02, acc03);
        *(float4*)(yp + 28) = make_float4(acc10, acc11, acc12, acc13);
    }
}

extern "C" void kernel_launch(void* const* d_in, const int* in_sizes, int n_in,
                              void* d_out, int out_size, void* d_ws, size_t ws_size,
                              hipStream_t stream) {
    const float* x  = (const float*)d_in[0];   // (1,64,28,28) fp32
    const float* w1 = (const float*)d_in[1];   // (128,32,3,3,2) fp32
    const float* w2 = (const float*)d_in[2];   // (64,3,2) fp32
    float* yout = (float*)d_out;               // (1,128,28,28) fp32

    fused_kernel<<<dim3(448), dim3(256), 0, stream>>>(x, w1, w2, yout);
}